// Round 1
// baseline (180.799 us; speedup 1.0000x reference)
//
#include <hip/hip_runtime.h>

#define HW 4096
#define C 64
#define H 8
#define D 8
#define SPLITS 8
#define KEYS_PER (HW / SPLITS)  // 512

// Kernel 1: q/k/v projections + per-head l2 normalization of q and k.
// One block per row, 192 threads = 3 waves: wave0 -> q cols, wave1 -> k cols,
// wave2 -> v cols. Row inputs x[row][*], y[row][*] have wave-uniform addresses
// -> scalar loads; W column reads are lane-coalesced.
__global__ __launch_bounds__(192) void proj_kernel(
    const float* __restrict__ x, const float* __restrict__ y,
    const float* __restrict__ Wq, const float* __restrict__ bq,
    const float* __restrict__ Wkv, const float* __restrict__ bkv,
    float* __restrict__ qn, float* __restrict__ kn, float* __restrict__ vv)
{
    const int row = blockIdx.x;
    const int t = threadIdx.x;
    const float* __restrict__ xr = x + (size_t)row * C;
    const float* __restrict__ yr = y + (size_t)row * C;

    float acc;
    if (t < 64) {
        const int j = t;
        acc = bq[j];
        #pragma unroll
        for (int i = 0; i < C; ++i) acc = fmaf(xr[i], Wq[i * C + j], acc);
    } else if (t < 128) {
        const int j = t - 64;
        acc = bkv[j];
        #pragma unroll
        for (int i = 0; i < C; ++i) acc = fmaf(yr[i], Wkv[i * 2 * C + j], acc);
    } else {
        const int j = t - 128;
        acc = bkv[C + j];
        #pragma unroll
        for (int i = 0; i < C; ++i) acc = fmaf(yr[i], Wkv[i * 2 * C + C + j], acc);
    }

    // sum of squares over each 8-lane head group (butterfly within wave)
    float ss = acc * acc;
    ss += __shfl_xor(ss, 1, 64);
    ss += __shfl_xor(ss, 2, 64);
    ss += __shfl_xor(ss, 4, 64);
    const float scale = 1.0f / fmaxf(sqrtf(ss), 1e-12f);

    const int j = (t < 64) ? t : (t < 128 ? (t - 64) : (t - 128));
    const int head = j >> 3;
    const int d = j & 7;
    const int idx = (head * HW + row) * D + d;  // [H][HW][D] layout
    if (t < 64)       qn[idx] = acc * scale;
    else if (t < 128) kn[idx] = acc * scale;
    else              vv[idx] = acc;
}

// Kernel 2: flash attention, fp32 VALU. Scores are in [-1,1] (cosine), so
// no running max is needed: p = exp(s) directly, denominator = sum p.
// Block = 8 waves; each wave owns the same 64 queries (1/lane, q in VGPRs)
// and a disjoint 512-key range. K/V addresses are wave-uniform -> s_load.
// Partials (o[8], l) combine by pure addition through LDS.
__global__ __launch_bounds__(64 * SPLITS) void attn_kernel(
    const float* __restrict__ qn, const float* __restrict__ kn,
    const float* __restrict__ vv, float* __restrict__ O)
{
    const int h  = blockIdx.x & (H - 1);
    const int qt = blockIdx.x >> 3;
    const int wave = __builtin_amdgcn_readfirstlane((int)(threadIdx.x >> 6));
    const int lane = threadIdx.x & 63;
    const int q = qt * 64 + lane;

    const float4* qp = (const float4*)(qn + ((size_t)(h * HW + q)) * D);
    const float4 qa = qp[0];
    const float4 qb = qp[1];

    const float* __restrict__ kbase = kn + (size_t)h * HW * D;
    const float* __restrict__ vbase = vv + (size_t)h * HW * D;

    float o0 = 0.f, o1 = 0.f, o2 = 0.f, o3 = 0.f;
    float o4 = 0.f, o5 = 0.f, o6 = 0.f, o7 = 0.f;
    float l = 0.f;

    const int k0 = wave * KEYS_PER;
    #pragma unroll 8
    for (int kk = k0; kk < k0 + KEYS_PER; ++kk) {
        // wave-uniform addresses -> scalar loads on the scalar pipe
        const float4* kp4 = (const float4*)(kbase + (size_t)kk * D);
        const float4 ka = kp4[0];
        const float4 kb = kp4[1];
        float s = qa.x * ka.x;
        s = fmaf(qa.y, ka.y, s);
        s = fmaf(qa.z, ka.z, s);
        s = fmaf(qa.w, ka.w, s);
        s = fmaf(qb.x, kb.x, s);
        s = fmaf(qb.y, kb.y, s);
        s = fmaf(qb.z, kb.z, s);
        s = fmaf(qb.w, kb.w, s);
        const float p = __expf(s);   // safe: s in [-1,1]
        l += p;
        const float4* vp4 = (const float4*)(vbase + (size_t)kk * D);
        const float4 va = vp4[0];
        const float4 vb = vp4[1];
        o0 = fmaf(p, va.x, o0);
        o1 = fmaf(p, va.y, o1);
        o2 = fmaf(p, va.z, o2);
        o3 = fmaf(p, va.w, o3);
        o4 = fmaf(p, vb.x, o4);
        o5 = fmaf(p, vb.y, o5);
        o6 = fmaf(p, vb.z, o6);
        o7 = fmaf(p, vb.w, o7);
    }

    __shared__ float sO[SPLITS][64][12];  // 12-stride: o[8], l, pad
    {
        float* dst = &sO[wave][lane][0];
        dst[0] = o0; dst[1] = o1; dst[2] = o2; dst[3] = o3;
        dst[4] = o4; dst[5] = o5; dst[6] = o6; dst[7] = o7;
        dst[8] = l;
    }
    __syncthreads();

    if (threadIdx.x < 64) {
        float a0 = 0.f, a1 = 0.f, a2 = 0.f, a3 = 0.f;
        float a4 = 0.f, a5 = 0.f, a6 = 0.f, a7 = 0.f, al = 0.f;
        #pragma unroll
        for (int s2 = 0; s2 < SPLITS; ++s2) {
            const float* src = &sO[s2][lane][0];
            a0 += src[0]; a1 += src[1]; a2 += src[2]; a3 += src[3];
            a4 += src[4]; a5 += src[5]; a6 += src[6]; a7 += src[7];
            al += src[8];
        }
        const float r = 1.0f / al;
        float4* op = (float4*)(O + (size_t)(qt * 64 + lane) * C + h * D);
        op[0] = make_float4(a0 * r, a1 * r, a2 * r, a3 * r);
        op[1] = make_float4(a4 * r, a5 * r, a6 * r, a7 * r);
    }
}

// Kernel 3: output projection O[4096x64] @ We[64x64] + be.
// 4 rows per block (1 row per wave); O-row addresses wave-uniform -> s_load,
// We column reads and output writes lane-coalesced.
__global__ __launch_bounds__(256) void outproj_kernel(
    const float* __restrict__ O, const float* __restrict__ We,
    const float* __restrict__ be, float* __restrict__ out)
{
    const int t = threadIdx.x;
    const int rlocal = __builtin_amdgcn_readfirstlane((int)(t >> 6));
    const int row = blockIdx.x * 4 + rlocal;
    const int j = t & 63;
    const float* __restrict__ orow = O + (size_t)row * C;
    float acc = be[j];
    #pragma unroll
    for (int i = 0; i < C; ++i) acc = fmaf(orow[i], We[i * C + j], acc);
    out[(size_t)row * C + j] = acc;
}

extern "C" void kernel_launch(void* const* d_in, const int* in_sizes, int n_in,
                              void* d_out, int out_size, void* d_ws, size_t ws_size,
                              hipStream_t stream) {
    const float* x   = (const float*)d_in[0];
    const float* y   = (const float*)d_in[1];
    const float* Wq  = (const float*)d_in[2];
    const float* bq  = (const float*)d_in[3];
    const float* Wkv = (const float*)d_in[4];
    const float* bkv = (const float*)d_in[5];
    const float* We  = (const float*)d_in[6];
    const float* be  = (const float*)d_in[7];
    float* out = (float*)d_out;

    float* ws = (float*)d_ws;
    const size_t per = (size_t)H * HW * D;  // 262144 floats
    float* qn = ws;
    float* kn = ws + per;
    float* vv = ws + 2 * per;
    float* O  = ws + 3 * per;   // [HW][C], total ws use = 4 MB

    hipLaunchKernelGGL(proj_kernel, dim3(HW), dim3(192), 0, stream,
                       x, y, Wq, bq, Wkv, bkv, qn, kn, vv);
    hipLaunchKernelGGL(attn_kernel, dim3(H * (HW / 64)), dim3(64 * SPLITS), 0, stream,
                       qn, kn, vv, O);
    hipLaunchKernelGGL(outproj_kernel, dim3(HW / 4), dim3(256), 0, stream,
                       O, We, be, out);
}

// Round 3
// 135.099 us; speedup vs baseline: 1.3383x; 1.3383x over previous
//
#include <hip/hip_runtime.h>

#define HW 4096
#define C 64
#define H 8
#define D 8
#define S 2                      // key splits across blocks
#define KEYS_PER_WAVE (HW / S / 8)   // 256
#define GROUPS (KEYS_PER_WAVE / 2)   // 128 two-key groups
#define L2E 1.44269504088896340736f

typedef _Float16 h2 __attribute__((ext_vector_type(2)));

static __device__ __forceinline__ h2 h2_of(unsigned int u) {
    return __builtin_bit_cast(h2, u);
}

static __device__ __forceinline__ float fdot2(h2 a, h2 b, float c) {
#if __has_builtin(__builtin_amdgcn_fdot2)
    return __builtin_amdgcn_fdot2(a, b, c, false);
#else
    return fmaf((float)a.x, (float)b.x, fmaf((float)a.y, (float)b.y, c));
#endif
}

static __device__ __forceinline__ float fast_exp2(float x) {
#if __has_builtin(__builtin_amdgcn_exp2f)
    return __builtin_amdgcn_exp2f(x);
#else
    return __exp2f(x);
#endif
}

static __device__ __forceinline__ h2 pack_h2(float a, float b) {
#if __has_builtin(__builtin_amdgcn_cvt_pkrtz)
    return __builtin_bit_cast(h2, __builtin_amdgcn_cvt_pkrtz(a, b));
#else
    h2 r; r.x = (_Float16)a; r.y = (_Float16)b; return r;
#endif
}

// Kernel 1: q/k/v projections + per-head l2 normalization, fp16 outputs.
// q pre-scaled by log2(e) so attention uses exp2 directly.
// Layouts: qh,kh = [H][HW][8] f16 ; vh = [H][HW/2][8][2] f16 (key-pair interleaved).
__global__ __launch_bounds__(192) void proj_kernel(
    const float* __restrict__ x, const float* __restrict__ y,
    const float* __restrict__ Wq, const float* __restrict__ bq,
    const float* __restrict__ Wkv, const float* __restrict__ bkv,
    _Float16* __restrict__ qh, _Float16* __restrict__ kh, _Float16* __restrict__ vh)
{
    const int row = blockIdx.x;
    const int t = threadIdx.x;
    const float* __restrict__ xr = x + (size_t)row * C;
    const float* __restrict__ yr = y + (size_t)row * C;

    float acc;
    if (t < 64) {
        const int j = t;
        acc = bq[j];
        #pragma unroll
        for (int i = 0; i < C; ++i) acc = fmaf(xr[i], Wq[i * C + j], acc);
    } else if (t < 128) {
        const int j = t - 64;
        acc = bkv[j];
        #pragma unroll
        for (int i = 0; i < C; ++i) acc = fmaf(yr[i], Wkv[i * 2 * C + j], acc);
    } else {
        const int j = t - 128;
        acc = bkv[C + j];
        #pragma unroll
        for (int i = 0; i < C; ++i) acc = fmaf(yr[i], Wkv[i * 2 * C + C + j], acc);
    }

    // sum of squares over each 8-lane head group (butterfly within wave)
    float ss = acc * acc;
    ss += __shfl_xor(ss, 1, 64);
    ss += __shfl_xor(ss, 2, 64);
    ss += __shfl_xor(ss, 4, 64);
    const float scale = 1.0f / fmaxf(sqrtf(ss), 1e-12f);

    const int j = (t < 64) ? t : (t < 128 ? (t - 64) : (t - 128));
    const int head = j >> 3;
    const int d = j & 7;
    if (t < 64) {
        qh[((size_t)(head * HW + row)) * D + d] = (_Float16)(acc * scale * L2E);
    } else if (t < 128) {
        kh[((size_t)(head * HW + row)) * D + d] = (_Float16)(acc * scale);
    } else {
        vh[(((size_t)(head * (HW / 2) + (row >> 1))) * D + d) * 2 + (row & 1)] = (_Float16)acc;
    }
}

// Kernel 2: flash attention, fp16 dot2 datapath, fp32 accumulate.
// Scores in [-1,1] (cosine) -> no running max. Grid = 512 q-tiles x S key
// splits = 1024 blocks (4/CU -> 32 waves/CU). Each wave: 64 queries (1/lane,
// q in VGPRs), 256-key disjoint range, K/V wave-uniform -> s_load.
// 2 keys per iteration: 8 fdot2 (QK) + 2 exp2 + pack + 1 fdot2 (l) + 8 fdot2 (PV).
__global__ __launch_bounds__(512) void attn_kernel(
    const _Float16* __restrict__ qh, const _Float16* __restrict__ kh,
    const _Float16* __restrict__ vh, float* __restrict__ po, float* __restrict__ pl)
{
    const int b = blockIdx.x;
    const int h = b & (H - 1);
    const int qt = (b >> 3) & 63;
    const int split = b >> 9;
    const int wave = __builtin_amdgcn_readfirstlane((int)(threadIdx.x >> 6));
    const int lane = threadIdx.x & 63;
    const int q = qt * 64 + lane;

    const uint4 qw = *(const uint4*)(qh + ((size_t)(h * HW + q)) * D);
    const h2 q0 = h2_of(qw.x), q1 = h2_of(qw.y), q2 = h2_of(qw.z), q3 = h2_of(qw.w);

    const _Float16* __restrict__ khh = kh + (size_t)h * HW * D;
    const _Float16* __restrict__ vhh = vh + (size_t)h * (HW / 2) * D * 2;

    float o0 = 0.f, o1 = 0.f, o2 = 0.f, o3 = 0.f;
    float o4 = 0.f, o5 = 0.f, o6 = 0.f, o7 = 0.f;
    float l = 0.f;
    const h2 one2 = { (_Float16)1.0f, (_Float16)1.0f };

    const int kg0 = (split * (HW / S) + wave * KEYS_PER_WAVE) / 2;  // pair index
    #pragma unroll 4
    for (int g = 0; g < GROUPS; ++g) {
        const int kp = kg0 + g;
        // two adjacent keys: 32B k, 32B v -> wave-uniform scalar loads
        const uint4* k4 = (const uint4*)(khh + (size_t)kp * 16);
        const uint4 ka = k4[0];
        const uint4 kb = k4[1];
        const uint4* v4 = (const uint4*)(vhh + (size_t)kp * 16);
        const uint4 va = v4[0];
        const uint4 vb = v4[1];

        float sa = fdot2(q0, h2_of(ka.x), 0.f);
        sa = fdot2(q1, h2_of(ka.y), sa);
        sa = fdot2(q2, h2_of(ka.z), sa);
        sa = fdot2(q3, h2_of(ka.w), sa);
        float sb = fdot2(q0, h2_of(kb.x), 0.f);
        sb = fdot2(q1, h2_of(kb.y), sb);
        sb = fdot2(q2, h2_of(kb.z), sb);
        sb = fdot2(q3, h2_of(kb.w), sb);

        const float pa = fast_exp2(sa);   // q pre-scaled by log2e; s in [-1.45,1.45]
        const float pb = fast_exp2(sb);
        const h2 p2 = pack_h2(pa, pb);
        l = fdot2(p2, one2, l);

        o0 = fdot2(p2, h2_of(va.x), o0);
        o1 = fdot2(p2, h2_of(va.y), o1);
        o2 = fdot2(p2, h2_of(va.z), o2);
        o3 = fdot2(p2, h2_of(va.w), o3);
        o4 = fdot2(p2, h2_of(vb.x), o4);
        o5 = fdot2(p2, h2_of(vb.y), o5);
        o6 = fdot2(p2, h2_of(vb.z), o6);
        o7 = fdot2(p2, h2_of(vb.w), o7);
    }

    __shared__ float sO[8][64][12];  // o[8], l, pad to 12
    {
        float* dst = &sO[wave][lane][0];
        dst[0] = o0; dst[1] = o1; dst[2] = o2; dst[3] = o3;
        dst[4] = o4; dst[5] = o5; dst[6] = o6; dst[7] = o7;
        dst[8] = l;
    }
    __syncthreads();

    if (threadIdx.x < 64) {
        float a0 = 0.f, a1 = 0.f, a2 = 0.f, a3 = 0.f;
        float a4 = 0.f, a5 = 0.f, a6 = 0.f, a7 = 0.f, al = 0.f;
        #pragma unroll
        for (int s2 = 0; s2 < 8; ++s2) {
            const float* src = &sO[s2][lane][0];
            a0 += src[0]; a1 += src[1]; a2 += src[2]; a3 += src[3];
            a4 += src[4]; a5 += src[5]; a6 += src[6]; a7 += src[7];
            al += src[8];
        }
        // unnormalized partial; combine across splits happens in outproj
        float4* op = (float4*)(po + ((size_t)(split * H + h) * HW + q) * 8);
        op[0] = make_float4(a0, a1, a2, a3);
        op[1] = make_float4(a4, a5, a6, a7);
        pl[(size_t)(split * H + h) * HW + q] = al;
    }
}

// Kernel 3: fused split-combine + normalize + output projection.
// 4 rows per block (1/wave). Lane c holds O_row[c] (= combined, normalized
// attention output channel c), broadcast through LDS, then 64x64 proj.
__global__ __launch_bounds__(256) void outproj_kernel(
    const float* __restrict__ po, const float* __restrict__ pl,
    const float* __restrict__ We, const float* __restrict__ be,
    float* __restrict__ out)
{
    const int t = threadIdx.x;
    const int wave = __builtin_amdgcn_readfirstlane((int)(t >> 6));
    const int lane = t & 63;
    const int r = blockIdx.x * 4 + wave;
    const int head = lane >> 3;
    const int d = lane & 7;

    const float oa = po[((size_t)(0 * H + head) * HW + r) * 8 + d];
    const float ob = po[((size_t)(1 * H + head) * HW + r) * 8 + d];
    const float la = pl[(size_t)(0 * H + head) * HW + r];
    const float lb = pl[(size_t)(1 * H + head) * HW + r];
    const float Oc = (oa + ob) / (la + lb);

    __shared__ float sO[4][64];
    sO[wave][lane] = Oc;
    __syncthreads();

    float acc = be[lane];
    const float4* s4 = (const float4*)(&sO[wave][0]);
    #pragma unroll
    for (int c4 = 0; c4 < 16; ++c4) {
        const float4 ov = s4[c4];   // wave-uniform broadcast read
        const int c = c4 * 4;
        acc = fmaf(ov.x, We[(c + 0) * C + lane], acc);
        acc = fmaf(ov.y, We[(c + 1) * C + lane], acc);
        acc = fmaf(ov.z, We[(c + 2) * C + lane], acc);
        acc = fmaf(ov.w, We[(c + 3) * C + lane], acc);
    }
    out[(size_t)r * C + lane] = acc;
}

extern "C" void kernel_launch(void* const* d_in, const int* in_sizes, int n_in,
                              void* d_out, int out_size, void* d_ws, size_t ws_size,
                              hipStream_t stream) {
    const float* x   = (const float*)d_in[0];
    const float* y   = (const float*)d_in[1];
    const float* Wq  = (const float*)d_in[2];
    const float* bq  = (const float*)d_in[3];
    const float* Wkv = (const float*)d_in[4];
    const float* bkv = (const float*)d_in[5];
    const float* We  = (const float*)d_in[6];
    const float* be  = (const float*)d_in[7];
    float* out = (float*)d_out;

    // ws layout (bytes):
    //   qh: [0, 512K)   kh: [512K, 1M)   vh: [1M, 1.5M)
    //   po: [1.5M, 3.5M)  (S*H*HW*8 fp32)   pl: [3.5M, 3.75M)
    char* ws = (char*)d_ws;
    _Float16* qh = (_Float16*)(ws);
    _Float16* kh = (_Float16*)(ws + (512u << 10));
    _Float16* vh = (_Float16*)(ws + (1024u << 10));
    float*    po = (float*)   (ws + (1536u << 10));
    float*    pl = (float*)   (ws + (3584u << 10));

    hipLaunchKernelGGL(proj_kernel, dim3(HW), dim3(192), 0, stream,
                       x, y, Wq, bq, Wkv, bkv, qh, kh, vh);
    hipLaunchKernelGGL(attn_kernel, dim3(512 * S), dim3(512), 0, stream,
                       qh, kh, vh, po, pl);
    hipLaunchKernelGGL(outproj_kernel, dim3(HW / 4), dim3(256), 0, stream,
                       po, pl, We, be, out);
}

// Round 4
// 128.631 us; speedup vs baseline: 1.4056x; 1.0503x over previous
//
#include <hip/hip_runtime.h>

#define HW 4096
#define C 64
#define H 8
#define D 8
#define S 2                      // key splits across blocks
#define KEYS_PER_WAVE (HW / S / 8)   // 256
#define GROUPS (KEYS_PER_WAVE / 2)   // 128 two-key groups
#define L2E 1.44269504088896340736f

typedef _Float16 h2 __attribute__((ext_vector_type(2)));

static __device__ __forceinline__ h2 h2_of(unsigned int u) {
    return __builtin_bit_cast(h2, u);
}

static __device__ __forceinline__ float fdot2(h2 a, h2 b, float c) {
#if __has_builtin(__builtin_amdgcn_fdot2)
    return __builtin_amdgcn_fdot2(a, b, c, false);
#else
    return fmaf((float)a.x, (float)b.x, fmaf((float)a.y, (float)b.y, c));
#endif
}

static __device__ __forceinline__ float fast_exp2(float x) {
#if __has_builtin(__builtin_amdgcn_exp2f)
    return __builtin_amdgcn_exp2f(x);
#else
    return __exp2f(x);
#endif
}

static __device__ __forceinline__ h2 pack_h2(float a, float b) {
#if __has_builtin(__builtin_amdgcn_cvt_pkrtz)
    return __builtin_bit_cast(h2, __builtin_amdgcn_cvt_pkrtz(a, b));
#else
    h2 r; r.x = (_Float16)a; r.y = (_Float16)b; return r;
#endif
}

static __device__ __forceinline__ float gnorm8(float a) {
    // sum of squares over each 8-lane group -> 1/max(sqrt,eps)
    float ss = a * a;
    ss += __shfl_xor(ss, 1, 64);
    ss += __shfl_xor(ss, 2, 64);
    ss += __shfl_xor(ss, 4, 64);
    return 1.0f / fmaxf(sqrtf(ss), 1e-12f);
}

// Kernel 1 v2: q/k/v projections + per-head l2 norm, fp16 outputs.
// 4 rows per wave: W column loads (1 dword/lane/i) amortized over 4 rows;
// row inputs are wave-uniform -> s_load_dwordx16 chunks.
// Layouts: qh,kh = [H][HW][8] f16 ; vh = [H][HW/2][8][2] f16 (key-pair interleaved).
__global__ __launch_bounds__(192) void proj_kernel(
    const float* __restrict__ x, const float* __restrict__ y,
    const float* __restrict__ Wq, const float* __restrict__ bq,
    const float* __restrict__ Wkv, const float* __restrict__ bkv,
    _Float16* __restrict__ qh, _Float16* __restrict__ kh, _Float16* __restrict__ vh)
{
    const int r0 = blockIdx.x * 4;
    const int wave = __builtin_amdgcn_readfirstlane((int)(threadIdx.x >> 6));
    const int j = threadIdx.x & 63;

    const float* __restrict__ W;
    const float* __restrict__ rows;
    int wstride;
    float bias;
    if (wave == 0)      { W = Wq + j;        wstride = C;     bias = bq[j];      rows = x + (size_t)r0 * C; }
    else if (wave == 1) { W = Wkv + j;       wstride = 2 * C; bias = bkv[j];     rows = y + (size_t)r0 * C; }
    else                { W = Wkv + C + j;   wstride = 2 * C; bias = bkv[C + j]; rows = y + (size_t)r0 * C; }

    float a0 = bias, a1 = bias, a2 = bias, a3 = bias;
    #pragma unroll
    for (int i = 0; i < C; ++i) {
        const float w = W[(size_t)i * wstride];   // lane-coalesced, reused 4x
        a0 = fmaf(rows[i],           w, a0);      // rows[*]: wave-uniform s_load
        a1 = fmaf(rows[C + i],       w, a1);
        a2 = fmaf(rows[2 * C + i],   w, a2);
        a3 = fmaf(rows[3 * C + i],   w, a3);
    }

    const int head = j >> 3;
    const int d = j & 7;
    if (wave == 0) {
        const float s0 = gnorm8(a0) * L2E, s1 = gnorm8(a1) * L2E;
        const float s2 = gnorm8(a2) * L2E, s3 = gnorm8(a3) * L2E;
        _Float16* p = qh + ((size_t)head * HW + r0) * D + d;
        p[0 * D] = (_Float16)(a0 * s0);
        p[1 * D] = (_Float16)(a1 * s1);
        p[2 * D] = (_Float16)(a2 * s2);
        p[3 * D] = (_Float16)(a3 * s3);
    } else if (wave == 1) {
        const float s0 = gnorm8(a0), s1 = gnorm8(a1);
        const float s2 = gnorm8(a2), s3 = gnorm8(a3);
        _Float16* p = kh + ((size_t)head * HW + r0) * D + d;
        p[0 * D] = (_Float16)(a0 * s0);
        p[1 * D] = (_Float16)(a1 * s1);
        p[2 * D] = (_Float16)(a2 * s2);
        p[3 * D] = (_Float16)(a3 * s3);
    } else {
        // pair index for r0..r0+3: (r0>>1) even/odd, (r0>>1)+1 even/odd
        _Float16* p = vh + (((size_t)head * (HW / 2) + (r0 >> 1)) * D + d) * 2;
        p[0]          = (_Float16)a0;   // pair 0, slot 0
        p[1]          = (_Float16)a1;   // pair 0, slot 1
        p[2 * D]      = (_Float16)a2;   // pair 1, slot 0
        p[2 * D + 1]  = (_Float16)a3;   // pair 1, slot 1
    }
}

// Kernel 2: flash attention, fp16 dot2 datapath, fp32 accumulate. (unchanged)
__global__ __launch_bounds__(512) void attn_kernel(
    const _Float16* __restrict__ qh, const _Float16* __restrict__ kh,
    const _Float16* __restrict__ vh, float* __restrict__ po, float* __restrict__ pl)
{
    const int b = blockIdx.x;
    const int h = b & (H - 1);
    const int qt = (b >> 3) & 63;
    const int split = b >> 9;
    const int wave = __builtin_amdgcn_readfirstlane((int)(threadIdx.x >> 6));
    const int lane = threadIdx.x & 63;
    const int q = qt * 64 + lane;

    const uint4 qw = *(const uint4*)(qh + ((size_t)(h * HW + q)) * D);
    const h2 q0 = h2_of(qw.x), q1 = h2_of(qw.y), q2 = h2_of(qw.z), q3 = h2_of(qw.w);

    const _Float16* __restrict__ khh = kh + (size_t)h * HW * D;
    const _Float16* __restrict__ vhh = vh + (size_t)h * (HW / 2) * D * 2;

    float o0 = 0.f, o1 = 0.f, o2 = 0.f, o3 = 0.f;
    float o4 = 0.f, o5 = 0.f, o6 = 0.f, o7 = 0.f;
    float l = 0.f;
    const h2 one2 = { (_Float16)1.0f, (_Float16)1.0f };

    const int kg0 = (split * (HW / S) + wave * KEYS_PER_WAVE) / 2;  // pair index
    #pragma unroll 4
    for (int g = 0; g < GROUPS; ++g) {
        const int kp = kg0 + g;
        const uint4* k4 = (const uint4*)(khh + (size_t)kp * 16);
        const uint4 ka = k4[0];
        const uint4 kb = k4[1];
        const uint4* v4 = (const uint4*)(vhh + (size_t)kp * 16);
        const uint4 va = v4[0];
        const uint4 vb = v4[1];

        float sa = fdot2(q0, h2_of(ka.x), 0.f);
        sa = fdot2(q1, h2_of(ka.y), sa);
        sa = fdot2(q2, h2_of(ka.z), sa);
        sa = fdot2(q3, h2_of(ka.w), sa);
        float sb = fdot2(q0, h2_of(kb.x), 0.f);
        sb = fdot2(q1, h2_of(kb.y), sb);
        sb = fdot2(q2, h2_of(kb.z), sb);
        sb = fdot2(q3, h2_of(kb.w), sb);

        const float pa = fast_exp2(sa);
        const float pb = fast_exp2(sb);
        const h2 p2 = pack_h2(pa, pb);
        l = fdot2(p2, one2, l);

        o0 = fdot2(p2, h2_of(va.x), o0);
        o1 = fdot2(p2, h2_of(va.y), o1);
        o2 = fdot2(p2, h2_of(va.z), o2);
        o3 = fdot2(p2, h2_of(va.w), o3);
        o4 = fdot2(p2, h2_of(vb.x), o4);
        o5 = fdot2(p2, h2_of(vb.y), o5);
        o6 = fdot2(p2, h2_of(vb.z), o6);
        o7 = fdot2(p2, h2_of(vb.w), o7);
    }

    __shared__ float sO[8][64][12];  // o[8], l, pad to 12
    {
        float* dst = &sO[wave][lane][0];
        dst[0] = o0; dst[1] = o1; dst[2] = o2; dst[3] = o3;
        dst[4] = o4; dst[5] = o5; dst[6] = o6; dst[7] = o7;
        dst[8] = l;
    }
    __syncthreads();

    if (threadIdx.x < 64) {
        float a0 = 0.f, a1 = 0.f, a2 = 0.f, a3 = 0.f;
        float a4 = 0.f, a5 = 0.f, a6 = 0.f, a7 = 0.f, al = 0.f;
        #pragma unroll
        for (int s2 = 0; s2 < 8; ++s2) {
            const float* src = &sO[s2][lane][0];
            a0 += src[0]; a1 += src[1]; a2 += src[2]; a3 += src[3];
            a4 += src[4]; a5 += src[5]; a6 += src[6]; a7 += src[7];
            al += src[8];
        }
        float4* op = (float4*)(po + ((size_t)(split * H + h) * HW + q) * 8);
        op[0] = make_float4(a0, a1, a2, a3);
        op[1] = make_float4(a4, a5, a6, a7);
        pl[(size_t)(split * H + h) * HW + q] = al;
    }
}

// Kernel 3 v2: fused split-combine + normalize + output projection.
// 16 rows per block (4 rows/wave): We column loads amortized over 4 rows;
// O rows broadcast from LDS via uniform-address ds_read_b128.
__global__ __launch_bounds__(256) void outproj_kernel(
    const float* __restrict__ po, const float* __restrict__ pl,
    const float* __restrict__ We, const float* __restrict__ be,
    float* __restrict__ out)
{
    const int t = threadIdx.x;
    const int wave = __builtin_amdgcn_readfirstlane((int)(t >> 6));
    const int lane = t & 63;
    const int rbase = blockIdx.x * 16 + wave * 4;
    const int head = lane >> 3;
    const int d = lane & 7;

    __shared__ float sO[16][64];

    #pragma unroll
    for (int rr = 0; rr < 4; ++rr) {
        const int r = rbase + rr;
        const float oa = po[((size_t)(0 * H + head) * HW + r) * 8 + d];
        const float ob = po[((size_t)(1 * H + head) * HW + r) * 8 + d];
        const float la = pl[(size_t)(0 * H + head) * HW + r];
        const float lb = pl[(size_t)(1 * H + head) * HW + r];
        sO[wave * 4 + rr][lane] = (oa + ob) / (la + lb);
    }
    __syncthreads();

    const float bias = be[lane];
    float a0 = bias, a1 = bias, a2 = bias, a3 = bias;
    #pragma unroll
    for (int i4 = 0; i4 < 16; ++i4) {
        const int i = i4 * 4;
        const float4 o0 = *(const float4*)&sO[wave * 4 + 0][i];  // uniform addr -> broadcast
        const float4 o1 = *(const float4*)&sO[wave * 4 + 1][i];
        const float4 o2 = *(const float4*)&sO[wave * 4 + 2][i];
        const float4 o3 = *(const float4*)&sO[wave * 4 + 3][i];
        const float w0 = We[(size_t)(i + 0) * C + lane];
        const float w1 = We[(size_t)(i + 1) * C + lane];
        const float w2 = We[(size_t)(i + 2) * C + lane];
        const float w3 = We[(size_t)(i + 3) * C + lane];
        a0 = fmaf(o0.x, w0, a0); a0 = fmaf(o0.y, w1, a0); a0 = fmaf(o0.z, w2, a0); a0 = fmaf(o0.w, w3, a0);
        a1 = fmaf(o1.x, w0, a1); a1 = fmaf(o1.y, w1, a1); a1 = fmaf(o1.z, w2, a1); a1 = fmaf(o1.w, w3, a1);
        a2 = fmaf(o2.x, w0, a2); a2 = fmaf(o2.y, w1, a2); a2 = fmaf(o2.z, w2, a2); a2 = fmaf(o2.w, w3, a2);
        a3 = fmaf(o3.x, w0, a3); a3 = fmaf(o3.y, w1, a3); a3 = fmaf(o3.z, w2, a3); a3 = fmaf(o3.w, w3, a3);
    }
    out[(size_t)(rbase + 0) * C + lane] = a0;
    out[(size_t)(rbase + 1) * C + lane] = a1;
    out[(size_t)(rbase + 2) * C + lane] = a2;
    out[(size_t)(rbase + 3) * C + lane] = a3;
}

extern "C" void kernel_launch(void* const* d_in, const int* in_sizes, int n_in,
                              void* d_out, int out_size, void* d_ws, size_t ws_size,
                              hipStream_t stream) {
    const float* x   = (const float*)d_in[0];
    const float* y   = (const float*)d_in[1];
    const float* Wq  = (const float*)d_in[2];
    const float* bq  = (const float*)d_in[3];
    const float* Wkv = (const float*)d_in[4];
    const float* bkv = (const float*)d_in[5];
    const float* We  = (const float*)d_in[6];
    const float* be  = (const float*)d_in[7];
    float* out = (float*)d_out;

    // ws layout (bytes):
    //   qh: [0, 512K)   kh: [512K, 1M)   vh: [1M, 1.5M)
    //   po: [1.5M, 3.5M)  (S*H*HW*8 fp32)   pl: [3.5M, 3.75M)
    char* ws = (char*)d_ws;
    _Float16* qh = (_Float16*)(ws);
    _Float16* kh = (_Float16*)(ws + (512u << 10));
    _Float16* vh = (_Float16*)(ws + (1024u << 10));
    float*    po = (float*)   (ws + (1536u << 10));
    float*    pl = (float*)   (ws + (3584u << 10));

    hipLaunchKernelGGL(proj_kernel, dim3(HW / 4), dim3(192), 0, stream,
                       x, y, Wq, bq, Wkv, bkv, qh, kh, vh);
    hipLaunchKernelGGL(attn_kernel, dim3(512 * S), dim3(512), 0, stream,
                       qh, kh, vh, po, pl);
    hipLaunchKernelGGL(outproj_kernel, dim3(HW / 16), dim3(256), 0, stream,
                       po, pl, We, be, out);
}

// Round 6
// 114.069 us; speedup vs baseline: 1.5850x; 1.1277x over previous
//
#include <hip/hip_runtime.h>

#define HW 4096
#define C 64
#define H 8
#define D 8
#define L2E 1.44269504088896340736f

typedef _Float16 h2 __attribute__((ext_vector_type(2)));
typedef _Float16 half4 __attribute__((ext_vector_type(4)));
typedef float f32x4 __attribute__((ext_vector_type(4)));

static __device__ __forceinline__ float fdot2(h2 a, h2 b, float c) {
    return __builtin_amdgcn_fdot2(a, b, c, false);
}

static __device__ __forceinline__ float fast_exp2(float x) {
#if __has_builtin(__builtin_amdgcn_exp2f)
    return __builtin_amdgcn_exp2f(x);
#else
    return __exp2f(x);
#endif
}

static __device__ __forceinline__ h2 pack_h2(float a, float b) {
    return __builtin_bit_cast(h2, __builtin_amdgcn_cvt_pkrtz(a, b));
}

static __device__ __forceinline__ half4 cat_h2(h2 lo, h2 hi) {
    uint2 u;
    u.x = __builtin_bit_cast(unsigned, lo);
    u.y = __builtin_bit_cast(unsigned, hi);
    return __builtin_bit_cast(half4, u);
}

static __device__ __forceinline__ f32x4 mfma16(half4 a, half4 b, f32x4 c) {
    return __builtin_amdgcn_mfma_f32_16x16x16f16(a, b, c, 0, 0, 0);
}

static __device__ __forceinline__ float gnorm8(float a) {
    float ss = a * a;
    ss += __shfl_xor(ss, 1, 64);
    ss += __shfl_xor(ss, 2, 64);
    ss += __shfl_xor(ss, 4, 64);
    return 1.0f / fmaxf(sqrtf(ss), 1e-12f);
}

// Kernel 1: q/k/v projections + per-head l2 norm, fp16 outputs.
// 4 rows per wave; W columns amortized over 4 rows; row inputs wave-uniform.
// Layouts: qh,kh = [H][HW][8] f16 (q pre-scaled by log2e); vt = [H*8][HW] f16
// (transposed V: lane j=(head*8+d) already holds rows r0..r0+3 for its channel
// -> direct half4 store, no LDS needed).
__global__ __launch_bounds__(192) void proj_kernel(
    const float* __restrict__ x, const float* __restrict__ y,
    const float* __restrict__ Wq, const float* __restrict__ bq,
    const float* __restrict__ Wkv, const float* __restrict__ bkv,
    _Float16* __restrict__ qh, _Float16* __restrict__ kh, _Float16* __restrict__ vt)
{
    const int r0 = blockIdx.x * 4;
    const int wave = __builtin_amdgcn_readfirstlane((int)(threadIdx.x >> 6));
    const int j = threadIdx.x & 63;

    const float* __restrict__ W;
    const float* __restrict__ rows;
    int wstride;
    float bias;
    if (wave == 0)      { W = Wq + j;        wstride = C;     bias = bq[j];      rows = x + (size_t)r0 * C; }
    else if (wave == 1) { W = Wkv + j;       wstride = 2 * C; bias = bkv[j];     rows = y + (size_t)r0 * C; }
    else                { W = Wkv + C + j;   wstride = 2 * C; bias = bkv[C + j]; rows = y + (size_t)r0 * C; }

    float a0 = bias, a1 = bias, a2 = bias, a3 = bias;
    #pragma unroll
    for (int i = 0; i < C; ++i) {
        const float w = W[(size_t)i * wstride];
        a0 = fmaf(rows[i],         w, a0);
        a1 = fmaf(rows[C + i],     w, a1);
        a2 = fmaf(rows[2 * C + i], w, a2);
        a3 = fmaf(rows[3 * C + i], w, a3);
    }

    const int head = j >> 3;
    const int d = j & 7;
    if (wave == 0) {
        const float s0 = gnorm8(a0) * L2E, s1 = gnorm8(a1) * L2E;
        const float s2 = gnorm8(a2) * L2E, s3 = gnorm8(a3) * L2E;
        _Float16* p = qh + ((size_t)head * HW + r0) * D + d;
        p[0 * D] = (_Float16)(a0 * s0);
        p[1 * D] = (_Float16)(a1 * s1);
        p[2 * D] = (_Float16)(a2 * s2);
        p[3 * D] = (_Float16)(a3 * s3);
    } else if (wave == 1) {
        const float s0 = gnorm8(a0), s1 = gnorm8(a1);
        const float s2 = gnorm8(a2), s3 = gnorm8(a3);
        _Float16* p = kh + ((size_t)head * HW + r0) * D + d;
        p[0 * D] = (_Float16)(a0 * s0);
        p[1 * D] = (_Float16)(a1 * s1);
        p[2 * D] = (_Float16)(a2 * s2);
        p[3 * D] = (_Float16)(a3 * s3);
    } else {
        // vt[j][r0..r0+3] = v rows for channel j — contiguous half4
        const h2 lo = pack_h2(a0, a1);
        const h2 hi = pack_h2(a2, a3);
        *(half4*)(vt + (size_t)j * HW + r0) = cat_h2(lo, hi);
    }
}

// Kernel 2: MFMA flash attention.
// Block = 8 waves = 8 key-splits of the same (head, 32-query pair of 16-tiles).
// Per wave, per 16-key tile:
//   MFMA1 (A=K-tile[m=key][k=dim], B=Q[k=dim][n=query], dims 8..15 zeroed)
//     -> C = S^T tile (rows=keys quad*4+r, col=query lane&15); cosine scores,
//        q pre-scaled by log2e -> p = exp2(score), no running max needed.
//   pack p to fp16: C-layout of S^T IS the B-fragment layout of the PV MFMA
//     (k=quad*4+i keys, n=query) -> NO transpose.
//   MFMA2 (A=V^T[m=dim][k=key] from vt, rows 8..15 zeroed, B=P) -> O accum.
// Epilogue: block-wide split-combine + softmax-normalize through LDS (1 barrier).
__global__ __launch_bounds__(512, 8) void attn_kernel(
    const _Float16* __restrict__ qh, const _Float16* __restrict__ kh,
    const _Float16* __restrict__ vt, float* __restrict__ Ofin)
{
    const int split = __builtin_amdgcn_readfirstlane((int)(threadIdx.x >> 6));
    const int lane = threadIdx.x & 63;
    const int n = lane & 15;      // query col (B1/C) / key row (A1)
    const int quad = lane >> 4;   // fragment quad
    const int h = blockIdx.x & 7;
    const int qp = blockIdx.x >> 3;   // 0..127
    const int q0 = qp * 32;           // two q-tiles: q0, q0+16

    const _Float16* __restrict__ qhh = qh + (size_t)h * HW * D;
    const _Float16* __restrict__ khh = kh + (size_t)h * HW * D;
    const _Float16* __restrict__ vth = vt + (size_t)h * D * HW;

    const half4 z4 = {};
    half4 qf0 = z4, qf1 = z4;
    if (quad < 2) {   // dims 8..15 of B1 stay zero
        qf0 = *(const half4*)(qhh + (size_t)(q0 + n) * D + quad * 4);
        qf1 = *(const half4*)(qhh + (size_t)(q0 + 16 + n) * D + quad * 4);
    }

    f32x4 o0 = {}, o1 = {};
    float l0 = 0.f, l1 = 0.f;
    const h2 one2 = { (_Float16)1.0f, (_Float16)1.0f };

    const int kt0 = split * 32;   // 32 16-key tiles per wave (512 keys)
    #pragma unroll 4
    for (int t = 0; t < 32; ++t) {
        const int kbase = (kt0 + t) * 16;
        // A1 = K-tile: lane holds K[key n][dims quad*4..+3]; dims>=8 -> 0
        half4 kf = *(const half4*)(khh + (size_t)(kbase + n) * D + (quad & 1) * 4);
        kf = (quad < 2) ? kf : z4;
        // A2 = V^T-tile: lane holds V_t[dim n][keys quad*4..+3]; dims>=8 -> 0
        half4 vf = *(const half4*)(vth + (size_t)(n & 7) * HW + kbase + quad * 4);
        vf = (n < 8) ? vf : z4;

        const f32x4 zc = {};
        f32x4 c0 = mfma16(kf, qf0, zc);   // S^T tile, q-tile 0
        f32x4 c1 = mfma16(kf, qf1, zc);   // S^T tile, q-tile 1

        const float pa0 = fast_exp2(c0[0]), pa1 = fast_exp2(c0[1]);
        const float pa2 = fast_exp2(c0[2]), pa3 = fast_exp2(c0[3]);
        const h2 lo0 = pack_h2(pa0, pa1), hi0 = pack_h2(pa2, pa3);
        l0 = fdot2(lo0, one2, l0);
        l0 = fdot2(hi0, one2, l0);
        const half4 pb0 = cat_h2(lo0, hi0);

        const float pb0e = fast_exp2(c1[0]), pb1e = fast_exp2(c1[1]);
        const float pb2e = fast_exp2(c1[2]), pb3e = fast_exp2(c1[3]);
        const h2 lo1 = pack_h2(pb0e, pb1e), hi1 = pack_h2(pb2e, pb3e);
        l1 = fdot2(lo1, one2, l1);
        l1 = fdot2(hi1, one2, l1);
        const half4 pb1 = cat_h2(lo1, hi1);

        o0 = mfma16(vf, pb0, o0);   // O[dim quad*4+r][query n]
        o1 = mfma16(vf, pb1, o1);
    }

    // reduce l over quads (lanes n, n+16, n+32, n+48 hold disjoint key subsets)
    l0 += __shfl_xor(l0, 16, 64); l0 += __shfl_xor(l0, 32, 64);
    l1 += __shfl_xor(l1, 16, 64); l1 += __shfl_xor(l1, 32, 64);

    __shared__ float sO[8][2][16][8];   // [split][tile][query][dim]
    __shared__ float sL[8][2][16];
    if (quad < 2) {   // dims 8..15 are zero rows — quads 2,3 hold zeros
        *(float4*)&sO[split][0][n][quad * 4] = make_float4(o0[0], o0[1], o0[2], o0[3]);
        *(float4*)&sO[split][1][n][quad * 4] = make_float4(o1[0], o1[1], o1[2], o1[3]);
    }
    if (lane < 16)      sL[split][0][lane]      = l0;
    else if (lane < 32) sL[split][1][lane - 16] = l1;
    __syncthreads();

    const int t = threadIdx.x;
    if (t < 256) {
        const int tile = t >> 7;
        const int n2 = (t >> 3) & 15;
        const int d2 = t & 7;
        float os = 0.f, ls = 0.f;
        #pragma unroll
        for (int s2 = 0; s2 < 8; ++s2) {
            os += sO[s2][tile][n2][d2];
            ls += sL[s2][tile][n2];
        }
        Ofin[((size_t)h * HW + q0 + tile * 16 + n2) * D + d2] = os / ls;
    }
}

// Kernel 3: output projection from normalized Ofin [H][HW][8].
// 16 rows per block (4 rows/wave); We columns amortized over 4 rows.
__global__ __launch_bounds__(256) void outproj_kernel(
    const float* __restrict__ Ofin, const float* __restrict__ We,
    const float* __restrict__ be, float* __restrict__ out)
{
    const int t = threadIdx.x;
    const int wave = __builtin_amdgcn_readfirstlane((int)(t >> 6));
    const int lane = t & 63;
    const int rbase = blockIdx.x * 16 + wave * 4;
    const int head = lane >> 3;
    const int d = lane & 7;

    __shared__ float sO[16][64];

    #pragma unroll
    for (int rr = 0; rr < 4; ++rr) {
        const int r = rbase + rr;
        sO[wave * 4 + rr][lane] = Ofin[((size_t)head * HW + r) * D + d];
    }
    __syncthreads();

    const float bias = be[lane];
    float a0 = bias, a1 = bias, a2 = bias, a3 = bias;
    #pragma unroll
    for (int i4 = 0; i4 < 16; ++i4) {
        const int i = i4 * 4;
        const float4 o0 = *(const float4*)&sO[wave * 4 + 0][i];
        const float4 o1 = *(const float4*)&sO[wave * 4 + 1][i];
        const float4 o2 = *(const float4*)&sO[wave * 4 + 2][i];
        const float4 o3 = *(const float4*)&sO[wave * 4 + 3][i];
        const float w0 = We[(size_t)(i + 0) * C + lane];
        const float w1 = We[(size_t)(i + 1) * C + lane];
        const float w2 = We[(size_t)(i + 2) * C + lane];
        const float w3 = We[(size_t)(i + 3) * C + lane];
        a0 = fmaf(o0.x, w0, a0); a0 = fmaf(o0.y, w1, a0); a0 = fmaf(o0.z, w2, a0); a0 = fmaf(o0.w, w3, a0);
        a1 = fmaf(o1.x, w0, a1); a1 = fmaf(o1.y, w1, a1); a1 = fmaf(o1.z, w2, a1); a1 = fmaf(o1.w, w3, a1);
        a2 = fmaf(o2.x, w0, a2); a2 = fmaf(o2.y, w1, a2); a2 = fmaf(o2.z, w2, a2); a2 = fmaf(o2.w, w3, a2);
        a3 = fmaf(o3.x, w0, a3); a3 = fmaf(o3.y, w1, a3); a3 = fmaf(o3.z, w2, a3); a3 = fmaf(o3.w, w3, a3);
    }
    out[(size_t)(rbase + 0) * C + lane] = a0;
    out[(size_t)(rbase + 1) * C + lane] = a1;
    out[(size_t)(rbase + 2) * C + lane] = a2;
    out[(size_t)(rbase + 3) * C + lane] = a3;
}

extern "C" void kernel_launch(void* const* d_in, const int* in_sizes, int n_in,
                              void* d_out, int out_size, void* d_ws, size_t ws_size,
                              hipStream_t stream) {
    const float* x   = (const float*)d_in[0];
    const float* y   = (const float*)d_in[1];
    const float* Wq  = (const float*)d_in[2];
    const float* bq  = (const float*)d_in[3];
    const float* Wkv = (const float*)d_in[4];
    const float* bkv = (const float*)d_in[5];
    const float* We  = (const float*)d_in[6];
    const float* be  = (const float*)d_in[7];
    float* out = (float*)d_out;

    // ws layout (bytes): qh [0,512K) kh [512K,1M) vt [1M,1.5M) Ofin [1.5M,2.5M)
    char* ws = (char*)d_ws;
    _Float16* qh   = (_Float16*)(ws);
    _Float16* kh   = (_Float16*)(ws + (512u << 10));
    _Float16* vt   = (_Float16*)(ws + (1024u << 10));
    float*    Ofin = (float*)   (ws + (1536u << 10));

    hipLaunchKernelGGL(proj_kernel, dim3(HW / 4), dim3(192), 0, stream,
                       x, y, Wq, bq, Wkv, bkv, qh, kh, vt);
    hipLaunchKernelGGL(attn_kernel, dim3(H * (HW / 32)), dim3(512), 0, stream,
                       qh, kh, vt, Ofin);
    hipLaunchKernelGGL(outproj_kernel, dim3(HW / 16), dim3(256), 0, stream,
                       Ofin, We, be, out);
}

// Round 7
// 97.861 us; speedup vs baseline: 1.8475x; 1.1656x over previous
//
#include <hip/hip_runtime.h>

#define HW 4096
#define C 64
#define H 8
#define D 8
#define S 8
#define KEYS_PER_SPLIT (HW / S)      // 512
#define TILES (KEYS_PER_SPLIT / 16)  // 32
#define L2E 1.44269504088896340736f
#define VROW 1032                    // sV row stride bytes (516 halves): uniform bank spread

typedef _Float16 h2 __attribute__((ext_vector_type(2)));
typedef _Float16 half4 __attribute__((ext_vector_type(4)));
typedef float f32x4 __attribute__((ext_vector_type(4)));

static __device__ __forceinline__ float fast_exp2(float x) {
#if __has_builtin(__builtin_amdgcn_exp2f)
    return __builtin_amdgcn_exp2f(x);
#else
    return __exp2f(x);
#endif
}

static __device__ __forceinline__ h2 pack_h2(float a, float b) {
    return __builtin_bit_cast(h2, __builtin_amdgcn_cvt_pkrtz(a, b));
}

static __device__ __forceinline__ half4 cat_h2(h2 lo, h2 hi) {
    uint2 u;
    u.x = __builtin_bit_cast(unsigned, lo);
    u.y = __builtin_bit_cast(unsigned, hi);
    return __builtin_bit_cast(half4, u);
}

static __device__ __forceinline__ f32x4 mfma16(half4 a, half4 b, f32x4 c) {
    return __builtin_amdgcn_mfma_f32_16x16x16f16(a, b, c, 0, 0, 0);
}

static __device__ __forceinline__ float gnorm8(float a) {
    float ss = a * a;
    ss += __shfl_xor(ss, 1, 64);
    ss += __shfl_xor(ss, 2, 64);
    ss += __shfl_xor(ss, 4, 64);
    return 1.0f / fmaxf(sqrtf(ss), 1e-12f);
}

// Kernel 1: q/k/v projections + per-head l2 norm, fp16 outputs. (unchanged)
// Layouts: qh,kh = [H][HW][8] f16 (q pre-scaled by log2e); vt = [H*8][HW] f16.
__global__ __launch_bounds__(192) void proj_kernel(
    const float* __restrict__ x, const float* __restrict__ y,
    const float* __restrict__ Wq, const float* __restrict__ bq,
    const float* __restrict__ Wkv, const float* __restrict__ bkv,
    _Float16* __restrict__ qh, _Float16* __restrict__ kh, _Float16* __restrict__ vt)
{
    const int r0 = blockIdx.x * 4;
    const int wave = __builtin_amdgcn_readfirstlane((int)(threadIdx.x >> 6));
    const int j = threadIdx.x & 63;

    const float* __restrict__ W;
    const float* __restrict__ rows;
    int wstride;
    float bias;
    if (wave == 0)      { W = Wq + j;        wstride = C;     bias = bq[j];      rows = x + (size_t)r0 * C; }
    else if (wave == 1) { W = Wkv + j;       wstride = 2 * C; bias = bkv[j];     rows = y + (size_t)r0 * C; }
    else                { W = Wkv + C + j;   wstride = 2 * C; bias = bkv[C + j]; rows = y + (size_t)r0 * C; }

    float a0 = bias, a1 = bias, a2 = bias, a3 = bias;
    #pragma unroll
    for (int i = 0; i < C; ++i) {
        const float w = W[(size_t)i * wstride];
        a0 = fmaf(rows[i],         w, a0);
        a1 = fmaf(rows[C + i],     w, a1);
        a2 = fmaf(rows[2 * C + i], w, a2);
        a3 = fmaf(rows[3 * C + i], w, a3);
    }

    const int head = j >> 3;
    const int d = j & 7;
    if (wave == 0) {
        const float s0 = gnorm8(a0) * L2E, s1 = gnorm8(a1) * L2E;
        const float s2 = gnorm8(a2) * L2E, s3 = gnorm8(a3) * L2E;
        _Float16* p = qh + ((size_t)head * HW + r0) * D + d;
        p[0 * D] = (_Float16)(a0 * s0);
        p[1 * D] = (_Float16)(a1 * s1);
        p[2 * D] = (_Float16)(a2 * s2);
        p[3 * D] = (_Float16)(a3 * s3);
    } else if (wave == 1) {
        const float s0 = gnorm8(a0), s1 = gnorm8(a1);
        const float s2 = gnorm8(a2), s3 = gnorm8(a3);
        _Float16* p = kh + ((size_t)head * HW + r0) * D + d;
        p[0 * D] = (_Float16)(a0 * s0);
        p[1 * D] = (_Float16)(a1 * s1);
        p[2 * D] = (_Float16)(a2 * s2);
        p[3 * D] = (_Float16)(a3 * s3);
    } else {
        const h2 lo = pack_h2(a0, a1);
        const h2 hi = pack_h2(a2, a3);
        uint2 u;
        u.x = __builtin_bit_cast(unsigned, lo);
        u.y = __builtin_bit_cast(unsigned, hi);
        *(half4*)(vt + (size_t)j * HW + r0) = __builtin_bit_cast(half4, u);
    }
}

// Kernel 2: LDS-staged MFMA flash attention.
// Block = (head h, 256 queries, key-split of 512 keys). 8 waves; wave w owns
// queries q0 = qg*256 + w*32 (two 16-tiles). Stage K (512x16B) + V (8 rows x
// 1KB) into LDS once, then 32 tiles of pure LDS-fed MFMA:
//   MFMA1 A=K-tile B=Q -> S^T (q zero-pads dims 8-15, so K quads 2-3 may hold
//   garbage); exp2 -> pack; C-layout of S^T == B-layout of PV MFMA (16x16x16).
//   V has a ones-row at channel 8 -> PV output row 8 = sum_k P = softmax denom
//   (rows 9-15 garbage -> land in unused accumulator rows).
// Partials po (unnormalized O) and pl (denominator) combined in outproj.
__global__ __launch_bounds__(512, 8) void attn_kernel(
    const _Float16* __restrict__ qh, const _Float16* __restrict__ kh,
    const _Float16* __restrict__ vt, float* __restrict__ po, float* __restrict__ pl)
{
    __shared__ __align__(16) char smem[512 * 16 + 16 * VROW];
    char* sV = smem + 512 * 16;   // 16 rows x VROW bytes; rows 0-7 data, 8 ones

    const int tid = threadIdx.x;
    const int wave = __builtin_amdgcn_readfirstlane(tid >> 6);
    const int lane = tid & 63;
    const int n = lane & 15;      // query col / key row / V-channel row
    const int quad = lane >> 4;

    const int b = blockIdx.x;
    const int h = b & 7;
    const int qg = (b >> 3) & 15;
    const int split = b >> 7;
    const int q0 = qg * 256 + wave * 32;
    const int k0 = split * KEYS_PER_SPLIT;

    const _Float16* __restrict__ qhh = qh + (size_t)h * HW * D;
    const _Float16* __restrict__ khh = kh + (size_t)h * HW * D;
    const _Float16* __restrict__ vth = vt + (size_t)h * D * HW;

    // stage K: thread t -> key k0+t, 16B row
    {
        const uint4 kd = *(const uint4*)(khh + (size_t)(k0 + tid) * D);
        *(uint4*)(smem + tid * 16) = kd;
    }
    // stage V: wave w -> channel row w, lane covers 16B (8 keys)
    {
        const uint4 vd = *(const uint4*)(vth + (size_t)wave * HW + k0 + lane * 8);
        char* dst = sV + wave * VROW + lane * 16;
        *(uint2*)dst       = make_uint2(vd.x, vd.y);
        *(uint2*)(dst + 8) = make_uint2(vd.z, vd.w);
    }
    // ones row (channel 8): 256 dwords of (1.0h,1.0h)
    if (tid < 256) *(unsigned*)(sV + 8 * VROW + tid * 4) = 0x3C003C00u;
    // rows 9-15 intentionally uninitialized (multiply into unused acc rows)

    // q fragments (B operand): quads 0-1 real dims, 2-3 zero
    const half4 z4 = {};
    half4 qf0 = z4, qf1 = z4;
    if (quad < 2) {
        qf0 = *(const half4*)(qhh + (size_t)(q0 + n) * D + quad * 4);
        qf1 = *(const half4*)(qhh + (size_t)(q0 + 16 + n) * D + quad * 4);
    }

    __syncthreads();

    f32x4 o0 = {}, o1 = {};
    const int kOff = n * 16 + (quad & 1) * 8;   // bytes into sK
    const int vOff = n * VROW + quad * 8;       // bytes into sV

    #pragma unroll 8
    for (int t = 0; t < TILES; ++t) {
        const half4 kf = __builtin_bit_cast(half4, *(const uint2*)(smem + kOff + t * 256));
        const half4 vf = __builtin_bit_cast(half4, *(const uint2*)(sV + vOff + t * 32));
        const f32x4 zc = {};
        f32x4 c0 = mfma16(kf, qf0, zc);   // S^T tile, q-tile 0
        f32x4 c1 = mfma16(kf, qf1, zc);   // S^T tile, q-tile 1
        const h2 lo0 = pack_h2(fast_exp2(c0[0]), fast_exp2(c0[1]));
        const h2 hi0 = pack_h2(fast_exp2(c0[2]), fast_exp2(c0[3]));
        const h2 lo1 = pack_h2(fast_exp2(c1[0]), fast_exp2(c1[1]));
        const h2 hi1 = pack_h2(fast_exp2(c1[2]), fast_exp2(c1[3]));
        o0 = mfma16(vf, cat_h2(lo0, hi0), o0);  // O rows 0-7 + denom row 8
        o1 = mfma16(vf, cat_h2(lo1, hi1), o1);
    }

    const size_t pbase = (size_t)(split * H + h) * HW;
    if (quad < 2) {
        *(float4*)(po + (pbase + q0 + n) * 8 + quad * 4)      = make_float4(o0[0], o0[1], o0[2], o0[3]);
        *(float4*)(po + (pbase + q0 + 16 + n) * 8 + quad * 4) = make_float4(o1[0], o1[1], o1[2], o1[3]);
    } else if (quad == 2) {
        pl[pbase + q0 + n]      = o0[0];   // acc row 8 = ones . P = denom
        pl[pbase + q0 + 16 + n] = o1[0];
    }
}

// Kernel 3: 8-split combine + normalize + output projection.
// 16 rows per block (4 rows/wave); We columns amortized over 4 rows.
__global__ __launch_bounds__(256) void outproj_kernel(
    const float* __restrict__ po, const float* __restrict__ pl,
    const float* __restrict__ We, const float* __restrict__ be,
    float* __restrict__ out)
{
    const int t = threadIdx.x;
    const int wave = __builtin_amdgcn_readfirstlane((int)(t >> 6));
    const int lane = t & 63;
    const int rbase = blockIdx.x * 16 + wave * 4;
    const int head = lane >> 3;
    const int d = lane & 7;

    __shared__ float sO[16][64];

    #pragma unroll
    for (int rr = 0; rr < 4; ++rr) {
        const int r = rbase + rr;
        float os = 0.f, ls = 0.f;
        #pragma unroll
        for (int s = 0; s < S; ++s) {
            os += po[((size_t)(s * H + head) * HW + r) * 8 + d];
            ls += pl[(size_t)(s * H + head) * HW + r];
        }
        sO[wave * 4 + rr][lane] = os / ls;
    }
    __syncthreads();

    const float bias = be[lane];
    float a0 = bias, a1 = bias, a2 = bias, a3 = bias;
    #pragma unroll
    for (int i4 = 0; i4 < 16; ++i4) {
        const int i = i4 * 4;
        const float4 o0 = *(const float4*)&sO[wave * 4 + 0][i];
        const float4 o1 = *(const float4*)&sO[wave * 4 + 1][i];
        const float4 o2 = *(const float4*)&sO[wave * 4 + 2][i];
        const float4 o3 = *(const float4*)&sO[wave * 4 + 3][i];
        const float w0 = We[(size_t)(i + 0) * C + lane];
        const float w1 = We[(size_t)(i + 1) * C + lane];
        const float w2 = We[(size_t)(i + 2) * C + lane];
        const float w3 = We[(size_t)(i + 3) * C + lane];
        a0 = fmaf(o0.x, w0, a0); a0 = fmaf(o0.y, w1, a0); a0 = fmaf(o0.z, w2, a0); a0 = fmaf(o0.w, w3, a0);
        a1 = fmaf(o1.x, w0, a1); a1 = fmaf(o1.y, w1, a1); a1 = fmaf(o1.z, w2, a1); a1 = fmaf(o1.w, w3, a1);
        a2 = fmaf(o2.x, w0, a2); a2 = fmaf(o2.y, w1, a2); a2 = fmaf(o2.z, w2, a2); a2 = fmaf(o2.w, w3, a2);
        a3 = fmaf(o3.x, w0, a3); a3 = fmaf(o3.y, w1, a3); a3 = fmaf(o3.z, w2, a3); a3 = fmaf(o3.w, w3, a3);
    }
    out[(size_t)(rbase + 0) * C + lane] = a0;
    out[(size_t)(rbase + 1) * C + lane] = a1;
    out[(size_t)(rbase + 2) * C + lane] = a2;
    out[(size_t)(rbase + 3) * C + lane] = a3;
}

extern "C" void kernel_launch(void* const* d_in, const int* in_sizes, int n_in,
                              void* d_out, int out_size, void* d_ws, size_t ws_size,
                              hipStream_t stream) {
    const float* x   = (const float*)d_in[0];
    const float* y   = (const float*)d_in[1];
    const float* Wq  = (const float*)d_in[2];
    const float* bq  = (const float*)d_in[3];
    const float* Wkv = (const float*)d_in[4];
    const float* bkv = (const float*)d_in[5];
    const float* We  = (const float*)d_in[6];
    const float* be  = (const float*)d_in[7];
    float* out = (float*)d_out;

    // ws layout (bytes): qh [0,512K) kh [512K,1M) vt [1M,1.5M)
    //                    po [1.5M, ~9.9M)  (S*H*HW*8 fp32)   pl [10M, ~11.1M)
    char* ws = (char*)d_ws;
    _Float16* qh = (_Float16*)(ws);
    _Float16* kh = (_Float16*)(ws + (512u << 10));
    _Float16* vt = (_Float16*)(ws + (1024u << 10));
    float*    po = (float*)   (ws + (1536u << 10));
    float*    pl = (float*)   (ws + (10240u << 10));

    hipLaunchKernelGGL(proj_kernel, dim3(HW / 4), dim3(192), 0, stream,
                       x, y, Wq, bq, Wkv, bkv, qh, kh, vt);
    hipLaunchKernelGGL(attn_kernel, dim3(H * (HW / 256) * S), dim3(512), 0, stream,
                       qh, kh, vt, po, pl);
    hipLaunchKernelGGL(outproj_kernel, dim3(HW / 16), dim3(256), 0, stream,
                       po, pl, We, be, out);
}

// Round 9
// 95.390 us; speedup vs baseline: 1.8954x; 1.0259x over previous
//
#include <hip/hip_runtime.h>

#define HW 4096
#define C 64
#define H 8
#define D 8
#define S 8
#define KEYS_PER_SPLIT (HW / S)      // 512
#define TILES (KEYS_PER_SPLIT / 32)  // 16 tiles of 32 keys
#define L2E 1.44269504088896340736f
#define KROW 24                      // padded K row stride (bytes): bank period 16 -> 2-way reads
#define VROW 1032                    // sV row stride bytes

typedef _Float16 h2 __attribute__((ext_vector_type(2)));
typedef _Float16 half4 __attribute__((ext_vector_type(4)));
typedef float f32x4 __attribute__((ext_vector_type(4)));
typedef float f32x16 __attribute__((ext_vector_type(16)));

static __device__ __forceinline__ float fast_exp2(float x) {
#if __has_builtin(__builtin_amdgcn_exp2f)
    return __builtin_amdgcn_exp2f(x);
#else
    return __exp2f(x);
#endif
}

static __device__ __forceinline__ h2 pack_h2(float a, float b) {
    return __builtin_bit_cast(h2, __builtin_amdgcn_cvt_pkrtz(a, b));
}

static __device__ __forceinline__ half4 cat_h2(h2 lo, h2 hi) {
    uint2 u;
    u.x = __builtin_bit_cast(unsigned, lo);
    u.y = __builtin_bit_cast(unsigned, hi);
    return __builtin_bit_cast(half4, u);
}

static __device__ __forceinline__ f32x16 mfma32(half4 a, half4 b, f32x16 c) {
    return __builtin_amdgcn_mfma_f32_32x32x8f16(a, b, c, 0, 0, 0);
}

static __device__ __forceinline__ float gnorm8(float a) {
    float ss = a * a;
    ss += __shfl_xor(ss, 1, 64);
    ss += __shfl_xor(ss, 2, 64);
    ss += __shfl_xor(ss, 4, 64);
    return 1.0f / fmaxf(sqrtf(ss), 1e-12f);
}

// Kernel 1: q/k/v projections + per-head l2 norm, fp16 outputs. (unchanged)
// Layouts: qh,kh = [H][HW][8] f16 (q pre-scaled by log2e); vt = [H*8][HW] f16.
__global__ __launch_bounds__(192) void proj_kernel(
    const float* __restrict__ x, const float* __restrict__ y,
    const float* __restrict__ Wq, const float* __restrict__ bq,
    const float* __restrict__ Wkv, const float* __restrict__ bkv,
    _Float16* __restrict__ qh, _Float16* __restrict__ kh, _Float16* __restrict__ vt)
{
    const int r0 = blockIdx.x * 4;
    const int wave = __builtin_amdgcn_readfirstlane((int)(threadIdx.x >> 6));
    const int j = threadIdx.x & 63;

    const float* __restrict__ W;
    const float* __restrict__ rows;
    int wstride;
    float bias;
    if (wave == 0)      { W = Wq + j;        wstride = C;     bias = bq[j];      rows = x + (size_t)r0 * C; }
    else if (wave == 1) { W = Wkv + j;       wstride = 2 * C; bias = bkv[j];     rows = y + (size_t)r0 * C; }
    else                { W = Wkv + C + j;   wstride = 2 * C; bias = bkv[C + j]; rows = y + (size_t)r0 * C; }

    float a0 = bias, a1 = bias, a2 = bias, a3 = bias;
    #pragma unroll
    for (int i = 0; i < C; ++i) {
        const float w = W[(size_t)i * wstride];
        a0 = fmaf(rows[i],         w, a0);
        a1 = fmaf(rows[C + i],     w, a1);
        a2 = fmaf(rows[2 * C + i], w, a2);
        a3 = fmaf(rows[3 * C + i], w, a3);
    }

    const int head = j >> 3;
    const int d = j & 7;
    if (wave == 0) {
        const float s0 = gnorm8(a0) * L2E, s1 = gnorm8(a1) * L2E;
        const float s2 = gnorm8(a2) * L2E, s3 = gnorm8(a3) * L2E;
        _Float16* p = qh + ((size_t)head * HW + r0) * D + d;
        p[0 * D] = (_Float16)(a0 * s0);
        p[1 * D] = (_Float16)(a1 * s1);
        p[2 * D] = (_Float16)(a2 * s2);
        p[3 * D] = (_Float16)(a3 * s3);
    } else if (wave == 1) {
        const float s0 = gnorm8(a0), s1 = gnorm8(a1);
        const float s2 = gnorm8(a2), s3 = gnorm8(a3);
        _Float16* p = kh + ((size_t)head * HW + r0) * D + d;
        p[0 * D] = (_Float16)(a0 * s0);
        p[1 * D] = (_Float16)(a1 * s1);
        p[2 * D] = (_Float16)(a2 * s2);
        p[3 * D] = (_Float16)(a3 * s3);
    } else {
        const h2 lo = pack_h2(a0, a1);
        const h2 hi = pack_h2(a2, a3);
        *(half4*)(vt + (size_t)j * HW + r0) = cat_h2(lo, hi);
    }
}

// Kernel 2: LDS-staged MFMA flash attention, 32x32x8 core (K=8 == d, no pad).
// Block = (head h, 256 queries, 512-key split). Wave w owns 32 queries.
// Per 32-key tile:
//   QK: one v_mfma_f32_32x32x8f16, A=K-tile (m=key, from padded-row sK),
//       B=Q (k=dim, regs) -> S^T 32x32 in f32x16 C-layout.
//   16 independent exp2 -> 4 half4 packs. C-layout reg group 4j+i holds key
//   8j+4*(lane>>5)+i == B-fragment k-index of PV MFMA j -> NO transpose.
//   PV: 4 x mfma(A=V^T fragment from sV, B=pb_j) accumulating O (32 ch x 32 q);
//       V channel row 8 = ones -> O reg 4 (row 8) = softmax denominator.
// Partials po/pl combined in outproj.
__global__ __launch_bounds__(512, 8) void attn_kernel(
    const _Float16* __restrict__ qh, const _Float16* __restrict__ kh,
    const _Float16* __restrict__ vt, float* __restrict__ po, float* __restrict__ pl)
{
    __shared__ __align__(16) char smem[512 * KROW + 16 * VROW];  // 12288 + 16512
    char* sV = smem + 512 * KROW;

    const int tid = threadIdx.x;
    const int wave = __builtin_amdgcn_readfirstlane(tid >> 6);
    const int lane = tid & 63;
    const int m = lane & 31;      // key row (QK A) / V channel (PV A) / query col (C)
    const int half = lane >> 5;   // K-dim half (QK) / key quad group (PV)

    const int b = blockIdx.x;
    const int h = b & 7;
    const int qg = (b >> 3) & 15;
    const int split = b >> 7;
    const int q0 = qg * 256 + wave * 32;
    const int k0 = split * KEYS_PER_SPLIT;

    const _Float16* __restrict__ qhh = qh + (size_t)h * HW * D;
    const _Float16* __restrict__ khh = kh + (size_t)h * HW * D;
    const _Float16* __restrict__ vth = vt + (size_t)h * D * HW;

    // stage K: thread t -> key k0+t, 16B data into 24B padded row (2 x b64)
    {
        const uint4 kd = *(const uint4*)(khh + (size_t)(k0 + tid) * D);
        char* dst = smem + tid * KROW;
        *(uint2*)dst       = make_uint2(kd.x, kd.y);
        *(uint2*)(dst + 8) = make_uint2(kd.z, kd.w);
    }
    // stage V: wave w -> channel row w, lane covers 16B (8 keys)
    {
        const uint4 vd = *(const uint4*)(vth + (size_t)wave * HW + k0 + lane * 8);
        char* dst = sV + wave * VROW + lane * 16;
        *(uint2*)dst       = make_uint2(vd.x, vd.y);
        *(uint2*)(dst + 8) = make_uint2(vd.z, vd.w);
    }
    // ones row (channel 8) -> PV output row 8 = denominator
    if (tid < 256) *(unsigned*)(sV + 8 * VROW + tid * 4) = 0x3C003C00u;
    // rows 9-15 uninitialized: feed only unused accumulator rows

    // Q fragment (B operand): lane holds q row q0+m, dims half*4..+3 (8B)
    const half4 qf = __builtin_bit_cast(half4,
        *(const uint2*)(qhh + (size_t)(q0 + m) * D + half * 4));

    __syncthreads();

    f32x16 O = {};
    const int kBase = m * KROW + half * 8;               // into sK, +t*32*KROW
    const int vBase = (lane & 15) * VROW + half * 8;     // into sV, +t*64 + j*16

    #pragma unroll 4
    for (int t = 0; t < TILES; ++t) {
        const half4 kf = __builtin_bit_cast(half4,
            *(const uint2*)(smem + kBase + t * (32 * KROW)));
        const f32x16 zc = {};
        const f32x16 c = mfma32(kf, qf, zc);   // S^T 32x32

        #pragma unroll
        for (int j = 0; j < 4; ++j) {
            const h2 lo = pack_h2(fast_exp2(c[4 * j + 0]), fast_exp2(c[4 * j + 1]));
            const h2 hi = pack_h2(fast_exp2(c[4 * j + 2]), fast_exp2(c[4 * j + 3]));
            const half4 pb = cat_h2(lo, hi);
            const half4 vf = __builtin_bit_cast(half4,
                *(const uint2*)(sV + vBase + t * 64 + j * 16));
            O = mfma32(vf, pb, O);
        }
    }

    // Epilogue: O C-layout row=(reg&3)+8*(reg>>2)+4*half, col=m.
    // half=0: regs 0-3 = channels 0-3, reg 4 = row 8 = denom; half=1: regs 0-3 = channels 4-7.
    const size_t pbase = (size_t)(split * H + h) * HW;
    *(float4*)(po + (pbase + q0 + m) * 8 + half * 4) = make_float4(O[0], O[1], O[2], O[3]);
    if (half == 0) pl[pbase + q0 + m] = O[4];
}

// Kernel 3: 8-split combine + normalize + output projection. (unchanged)
__global__ __launch_bounds__(256) void outproj_kernel(
    const float* __restrict__ po, const float* __restrict__ pl,
    const float* __restrict__ We, const float* __restrict__ be,
    float* __restrict__ out)
{
    const int t = threadIdx.x;
    const int wave = __builtin_amdgcn_readfirstlane((int)(t >> 6));
    const int lane = t & 63;
    const int rbase = blockIdx.x * 16 + wave * 4;
    const int head = lane >> 3;
    const int d = lane & 7;

    __shared__ float sO[16][64];

    #pragma unroll
    for (int rr = 0; rr < 4; ++rr) {
        const int r = rbase + rr;
        float os = 0.f, ls = 0.f;
        #pragma unroll
        for (int s = 0; s < S; ++s) {
            os += po[((size_t)(s * H + head) * HW + r) * 8 + d];
            ls += pl[(size_t)(s * H + head) * HW + r];
        }
        sO[wave * 4 + rr][lane] = os / ls;
    }
    __syncthreads();

    const float bias = be[lane];
    float a0 = bias, a1 = bias, a2 = bias, a3 = bias;
    #pragma unroll
    for (int i4 = 0; i4 < 16; ++i4) {
        const int i = i4 * 4;
        const float4 o0 = *(const float4*)&sO[wave * 4 + 0][i];
        const float4 o1 = *(const float4*)&sO[wave * 4 + 1][i];
        const float4 o2 = *(const float4*)&sO[wave * 4 + 2][i];
        const float4 o3 = *(const float4*)&sO[wave * 4 + 3][i];
        const float w0 = We[(size_t)(i + 0) * C + lane];
        const float w1 = We[(size_t)(i + 1) * C + lane];
        const float w2 = We[(size_t)(i + 2) * C + lane];
        const float w3 = We[(size_t)(i + 3) * C + lane];
        a0 = fmaf(o0.x, w0, a0); a0 = fmaf(o0.y, w1, a0); a0 = fmaf(o0.z, w2, a0); a0 = fmaf(o0.w, w3, a0);
        a1 = fmaf(o1.x, w0, a1); a1 = fmaf(o1.y, w1, a1); a1 = fmaf(o1.z, w2, a1); a1 = fmaf(o1.w, w3, a1);
        a2 = fmaf(o2.x, w0, a2); a2 = fmaf(o2.y, w1, a2); a2 = fmaf(o2.z, w2, a2); a2 = fmaf(o2.w, w3, a2);
        a3 = fmaf(o3.x, w0, a3); a3 = fmaf(o3.y, w1, a3); a3 = fmaf(o3.z, w2, a3); a3 = fmaf(o3.w, w3, a3);
    }
    out[(size_t)(rbase + 0) * C + lane] = a0;
    out[(size_t)(rbase + 1) * C + lane] = a1;
    out[(size_t)(rbase + 2) * C + lane] = a2;
    out[(size_t)(rbase + 3) * C + lane] = a3;
}

extern "C" void kernel_launch(void* const* d_in, const int* in_sizes, int n_in,
                              void* d_out, int out_size, void* d_ws, size_t ws_size,
                              hipStream_t stream) {
    const float* x   = (const float*)d_in[0];
    const float* y   = (const float*)d_in[1];
    const float* Wq  = (const float*)d_in[2];
    const float* bq  = (const float*)d_in[3];
    const float* Wkv = (const float*)d_in[4];
    const float* bkv = (const float*)d_in[5];
    const float* We  = (const float*)d_in[6];
    const float* be  = (const float*)d_in[7];
    float* out = (float*)d_out;

    // ws layout (bytes): qh [0,512K) kh [512K,1M) vt [1M,1.5M)
    //                    po [1.5M, ~9.9M)  (S*H*HW*8 fp32)   pl [10M, ~11.1M)
    char* ws = (char*)d_ws;
    _Float16* qh = (_Float16*)(ws);
    _Float16* kh = (_Float16*)(ws + (512u << 10));
    _Float16* vt = (_Float16*)(ws + (1024u << 10));
    float*    po = (float*)   (ws + (1536u << 10));
    float*    pl = (float*)   (ws + (10240u << 10));

    hipLaunchKernelGGL(proj_kernel, dim3(HW / 4), dim3(192), 0, stream,
                       x, y, Wq, bq, Wkv, bkv, qh, kh, vt);
    hipLaunchKernelGGL(attn_kernel, dim3(H * (HW / 256) * S), dim3(512), 0, stream,
                       qh, kh, vt, po, pl);
    hipLaunchKernelGGL(outproj_kernel, dim3(HW / 16), dim3(256), 0, stream,
                       po, pl, We, be, out);
}